// Round 1
// baseline (1173.978 us; speedup 1.0000x reference)
//
#include <hip/hip_runtime.h>

// GAT node regressor: 3 GAT layers (HID=64, 4 heads x 16) + linear head.
// Strategy: build CSR-by-dst once per call (hist/scan/scatter), then per layer:
//   k_gemm: xh = h@W (LDS-tiled fp32) fused with al_s/al_d head reductions
//   k_agg : wave-per-dst-node gather: pass1 segment-max, pass2 exp-sum + message
//           accumulate (alpha denominator factored out), bias+relu epilogue;
//           layer 2 fuses the final h@out_w dot via wave shfl reduction.

__global__ __launch_bounds__(256) void k_zero(int* p, int n) {
    int i = blockIdx.x * 256 + threadIdx.x;
    if (i < n) p[i] = 0;
}

__global__ __launch_bounds__(256) void k_hist(const int* __restrict__ dst, int* __restrict__ counts, int e) {
    int i = blockIdx.x * 256 + threadIdx.x;
    if (i < e) atomicAdd(&counts[dst[i]], 1);
}

__global__ __launch_bounds__(256) void k_scan_a(const int* __restrict__ counts, int* __restrict__ partials, int n) {
    __shared__ int s[256];
    int t = threadIdx.x;
    int i = blockIdx.x * 256 + t;
    s[t] = (i < n) ? counts[i] : 0;
    __syncthreads();
    for (int o = 128; o; o >>= 1) {
        if (t < o) s[t] += s[t + o];
        __syncthreads();
    }
    if (t == 0) partials[blockIdx.x] = s[0];
}

__global__ __launch_bounds__(512) void k_scan_b(int* partials, int nblk) {
    __shared__ int s[512];
    int t = threadIdx.x;
    int v = (t < nblk) ? partials[t] : 0;
    s[t] = v;
    __syncthreads();
    for (int o = 1; o < 512; o <<= 1) {
        int add = (t >= o) ? s[t - o] : 0;
        __syncthreads();
        s[t] += add;
        __syncthreads();
    }
    if (t < nblk) partials[t] = s[t] - v;  // exclusive scan of block sums
}

__global__ __launch_bounds__(256) void k_scan_c(const int* __restrict__ counts, const int* __restrict__ partials,
                                                int* __restrict__ offs, int* __restrict__ fill, int n) {
    __shared__ int s[256];
    int t = threadIdx.x;
    int i = blockIdx.x * 256 + t;
    int v = (i < n) ? counts[i] : 0;
    s[t] = v;
    __syncthreads();
    for (int o = 1; o < 256; o <<= 1) {
        int add = (t >= o) ? s[t - o] : 0;
        __syncthreads();
        s[t] += add;
        __syncthreads();
    }
    int excl = s[t] - v + partials[blockIdx.x];
    if (i < n) {
        offs[i] = excl;
        fill[i] = excl;
        if (i == n - 1) offs[n] = excl + v;
    }
}

__global__ __launch_bounds__(256) void k_scatter(const int* __restrict__ src, const int* __restrict__ dst,
                                                 int* fill, int* __restrict__ ssrc, int e) {
    int i = blockIdx.x * 256 + threadIdx.x;
    if (i < e) {
        int p = atomicAdd(&fill[dst[i]], 1);
        ssrc[p] = src[i];
    }
}

// xh = h @ W  (h: [n, D_IN], W: [D_IN, 64]) fused with per-head attention logits:
// al_s[v,h] = sum_c xh[v,h*16+c]*asrc[h,c], al_d likewise.
// Block = 256 threads = 64-node tile; thread (cg,ng) computes 4 nodes x 4 cols.
// h tile staged in LDS (padded stride, 2-way-at-most bank aliasing = free);
// W read through L1 (32KB, shared by all blocks).
template <int D_IN>
__global__ __launch_bounds__(256) void k_gemm(const float* __restrict__ h, const float* __restrict__ W,
                                              const float* __restrict__ asrc, const float* __restrict__ adst,
                                              float* __restrict__ xh, float* __restrict__ als,
                                              float* __restrict__ ald, int n) {
    constexpr int HSTR = D_IN + 4;  // pad keeps float4 alignment (4-elem) and breaks bank stride
    __shared__ float hlds[64 * HSTR];
    int t = threadIdx.x;
    int node0 = blockIdx.x * 64;
    constexpr int HTOT = 64 * D_IN / 4;
    for (int i = t; i < HTOT; i += 256) {
        int f = i * 4;
        int nd = f / D_IN, k = f % D_IN;  // D_IN % 4 == 0 -> float4 stays in-row
        float4 val = make_float4(0.f, 0.f, 0.f, 0.f);
        if (node0 + nd < n) val = *(const float4*)(h + (size_t)(node0 + nd) * D_IN + k);
        *(float4*)(hlds + nd * HSTR + k) = val;
    }
    __syncthreads();
    int cg = t & 15, ng = t >> 4;  // cols 4*cg..4*cg+3, nodes 4*ng..4*ng+3
    float4 acc[4];
#pragma unroll
    for (int i = 0; i < 4; ++i) acc[i] = make_float4(0.f, 0.f, 0.f, 0.f);
    for (int k = 0; k < D_IN; k += 4) {
        float4 w0 = *(const float4*)(W + (size_t)(k + 0) * 64 + cg * 4);
        float4 w1 = *(const float4*)(W + (size_t)(k + 1) * 64 + cg * 4);
        float4 w2 = *(const float4*)(W + (size_t)(k + 2) * 64 + cg * 4);
        float4 w3 = *(const float4*)(W + (size_t)(k + 3) * 64 + cg * 4);
#pragma unroll
        for (int i = 0; i < 4; ++i) {
            float4 hv = *(const float4*)(hlds + (ng * 4 + i) * HSTR + k);
            acc[i].x += hv.x * w0.x + hv.y * w1.x + hv.z * w2.x + hv.w * w3.x;
            acc[i].y += hv.x * w0.y + hv.y * w1.y + hv.z * w2.y + hv.w * w3.y;
            acc[i].z += hv.x * w0.z + hv.y * w1.z + hv.z * w2.z + hv.w * w3.z;
            acc[i].w += hv.x * w0.w + hv.y * w1.w + hv.z * w2.w + hv.w * w3.w;
        }
    }
    // asrc/adst are [4][16] flat = indexed exactly by col
    float4 as4 = *(const float4*)(asrc + cg * 4);
    float4 ad4 = *(const float4*)(adst + cg * 4);
#pragma unroll
    for (int i = 0; i < 4; ++i) {
        int node = node0 + ng * 4 + i;
        float ps = acc[i].x * as4.x + acc[i].y * as4.y + acc[i].z * as4.z + acc[i].w * as4.w;
        float pd = acc[i].x * ad4.x + acc[i].y * ad4.y + acc[i].z * ad4.z + acc[i].w * ad4.w;
        ps += __shfl_xor(ps, 1, 64);
        ps += __shfl_xor(ps, 2, 64);
        pd += __shfl_xor(pd, 1, 64);
        pd += __shfl_xor(pd, 2, 64);
        if (node < n) {
            *(float4*)(xh + (size_t)node * 64 + cg * 4) = acc[i];
            if ((cg & 3) == 0) {
                als[node * 4 + (cg >> 2)] = ps;
                ald[node * 4 + (cg >> 2)] = pd;
            }
        }
    }
}

// One wave per destination node; lane = feature column (head = lane>>4).
// Self-loop (reference appends it) handled inline as u == v.
__global__ __launch_bounds__(256) void k_agg(const float* __restrict__ xh, const float* __restrict__ als,
                                             const float* __restrict__ ald, const int* __restrict__ offs,
                                             const int* __restrict__ ssrc, const float* __restrict__ bias,
                                             float* __restrict__ hout, const float* __restrict__ outw,
                                             const float* __restrict__ outb, float* __restrict__ fout, int n) {
    int wid = (blockIdx.x * 256 + threadIdx.x) >> 6;
    if (wid >= n) return;
    int lane = threadIdx.x & 63;
    int head = lane >> 4;
    int v = wid;
    int start = offs[v], end = offs[v + 1];
    float ald_v = ald[v * 4 + head];
    float als_v = als[v * 4 + head];
    float e_self = als_v + ald_v;
    e_self = e_self >= 0.f ? e_self : 0.2f * e_self;
    // pass 1: segment max (exact, order-free)
    float m = e_self;
    for (int j = start; j < end; ++j) {
        int u = ssrc[j];
        float a = als[u * 4 + head] + ald_v;
        a = a >= 0.f ? a : 0.2f * a;
        m = fmaxf(m, a);
    }
    // pass 2: z = sum exp(e-m); acc = sum exp(e-m)*xh[u]; alpha denom factored out
    float p = __expf(e_self - m);
    float z = p;
    float acc = p * xh[(size_t)v * 64 + lane];
    for (int j = start; j < end; ++j) {
        int u = ssrc[j];
        float a = als[u * 4 + head] + ald_v;
        a = a >= 0.f ? a : 0.2f * a;
        float pe = __expf(a - m);
        z += pe;
        acc += pe * xh[(size_t)u * 64 + lane];
    }
    float o = acc / (z + 1e-16f) + bias[lane];
    o = fmaxf(o, 0.f);  // relu after every layer
    if (outw) {
        // fused final linear head: dot(h[v], out_w) + out_b
        float tsum = o * outw[lane];
#pragma unroll
        for (int d = 32; d; d >>= 1) tsum += __shfl_down(tsum, d, 64);
        if (lane == 0) fout[v] = tsum + outb[0];
    } else {
        hout[(size_t)v * 64 + lane] = o;
    }
}

extern "C" void kernel_launch(void* const* d_in, const int* in_sizes, int n_in,
                              void* d_out, int out_size, void* d_ws, size_t ws_size,
                              hipStream_t stream) {
    const float* x = (const float*)d_in[0];
    const int* ei = (const int*)d_in[1];
    const float* w[3] = {(const float*)d_in[2], (const float*)d_in[6], (const float*)d_in[10]};
    const float* as[3] = {(const float*)d_in[3], (const float*)d_in[7], (const float*)d_in[11]};
    const float* ad[3] = {(const float*)d_in[4], (const float*)d_in[8], (const float*)d_in[12]};
    const float* b[3] = {(const float*)d_in[5], (const float*)d_in[9], (const float*)d_in[13]};
    const float* outw = (const float*)d_in[14];
    const float* outb = (const float*)d_in[15];

    const int N = in_sizes[0] / 128;
    const int E = in_sizes[1] / 2;
    const int* src = ei;
    const int* dst = ei + E;

    char* ws = (char*)d_ws;
    auto alloc = [&](size_t bytes) -> void* {
        void* p = (void*)ws;
        ws += (bytes + 255) & ~(size_t)255;
        return p;
    };
    int* counts = (int*)alloc((size_t)N * 4);
    int* offs = (int*)alloc((size_t)(N + 1) * 4);
    int* fill = (int*)alloc((size_t)N * 4);
    int* partials = (int*)alloc(512 * 4);
    int* ssrc = (int*)alloc((size_t)E * 4);
    float* xh = (float*)alloc((size_t)N * 64 * 4);
    float* hbuf = (float*)alloc((size_t)N * 64 * 4);
    float* als = (float*)alloc((size_t)N * 4 * 4);
    float* ald = (float*)alloc((size_t)N * 4 * 4);

    const int nblk = (N + 255) / 256;  // 391 <= 512 (k_scan_b capacity)
    k_zero<<<(N + 255) / 256, 256, 0, stream>>>(counts, N);
    k_hist<<<(E + 255) / 256, 256, 0, stream>>>(dst, counts, E);
    k_scan_a<<<nblk, 256, 0, stream>>>(counts, partials, N);
    k_scan_b<<<1, 512, 0, stream>>>(partials, nblk);
    k_scan_c<<<nblk, 256, 0, stream>>>(counts, partials, offs, fill, N);
    k_scatter<<<(E + 255) / 256, 256, 0, stream>>>(src, dst, fill, ssrc, E);

    const int gblocks = (N + 63) / 64;
    const int ablocks = (N + 3) / 4;  // 4 waves (nodes) per 256-thread block

    k_gemm<128><<<gblocks, 256, 0, stream>>>(x, w[0], as[0], ad[0], xh, als, ald, N);
    k_agg<<<ablocks, 256, 0, stream>>>(xh, als, ald, offs, ssrc, b[0], hbuf, nullptr, nullptr, nullptr, N);
    k_gemm<64><<<gblocks, 256, 0, stream>>>(hbuf, w[1], as[1], ad[1], xh, als, ald, N);
    k_agg<<<ablocks, 256, 0, stream>>>(xh, als, ald, offs, ssrc, b[1], hbuf, nullptr, nullptr, nullptr, N);
    k_gemm<64><<<gblocks, 256, 0, stream>>>(hbuf, w[2], as[2], ad[2], xh, als, ald, N);
    k_agg<<<ablocks, 256, 0, stream>>>(xh, als, ald, offs, ssrc, b[2], nullptr, outw, outb, (float*)d_out, N);
}

// Round 2
// 703.797 us; speedup vs baseline: 1.6681x; 1.6681x over previous
//
#include <hip/hip_runtime.h>

// GAT node regressor: 3 GAT layers (HID=64, 4 heads x 16) + linear head.
// CSR-by-dst built once per call (hist/scan/scatter), then per layer:
//   k_gemm: xh = h@W (LDS-tiled fp32) fused with al_s/al_d head reductions
//   k_agg : wave-per-dst-node gather, SINGLE pass (m fixed at e_self per head),
//           chunked: 64 edge logits computed lane-parallel (all 4 heads) and
//           stashed in LDS, then an MLP-4 accumulate loop over xh rows.
//           Layer 2 fuses the final h@out_w dot via wave shfl reduction.

__global__ __launch_bounds__(256) void k_zero(int* p, int n) {
    int i = blockIdx.x * 256 + threadIdx.x;
    if (i < n) p[i] = 0;
}

__global__ __launch_bounds__(256) void k_hist(const int* __restrict__ dst, int* __restrict__ counts, int e) {
    int i = blockIdx.x * 256 + threadIdx.x;
    if (i < e) atomicAdd(&counts[dst[i]], 1);
}

__global__ __launch_bounds__(256) void k_scan_a(const int* __restrict__ counts, int* __restrict__ partials, int n) {
    __shared__ int s[256];
    int t = threadIdx.x;
    int i = blockIdx.x * 256 + t;
    s[t] = (i < n) ? counts[i] : 0;
    __syncthreads();
    for (int o = 128; o; o >>= 1) {
        if (t < o) s[t] += s[t + o];
        __syncthreads();
    }
    if (t == 0) partials[blockIdx.x] = s[0];
}

__global__ __launch_bounds__(512) void k_scan_b(int* partials, int nblk) {
    __shared__ int s[512];
    int t = threadIdx.x;
    int v = (t < nblk) ? partials[t] : 0;
    s[t] = v;
    __syncthreads();
    for (int o = 1; o < 512; o <<= 1) {
        int add = (t >= o) ? s[t - o] : 0;
        __syncthreads();
        s[t] += add;
        __syncthreads();
    }
    if (t < nblk) partials[t] = s[t] - v;  // exclusive scan of block sums
}

__global__ __launch_bounds__(256) void k_scan_c(const int* __restrict__ counts, const int* __restrict__ partials,
                                                int* __restrict__ offs, int* __restrict__ fill, int n) {
    __shared__ int s[256];
    int t = threadIdx.x;
    int i = blockIdx.x * 256 + t;
    int v = (i < n) ? counts[i] : 0;
    s[t] = v;
    __syncthreads();
    for (int o = 1; o < 256; o <<= 1) {
        int add = (t >= o) ? s[t - o] : 0;
        __syncthreads();
        s[t] += add;
        __syncthreads();
    }
    int excl = s[t] - v + partials[blockIdx.x];
    if (i < n) {
        offs[i] = excl;
        fill[i] = excl;
        if (i == n - 1) offs[n] = excl + v;
    }
}

__global__ __launch_bounds__(256) void k_scatter(const int* __restrict__ src, const int* __restrict__ dst,
                                                 int* fill, int* __restrict__ ssrc, int e) {
    int i = blockIdx.x * 256 + threadIdx.x;
    if (i < e) {
        int p = atomicAdd(&fill[dst[i]], 1);
        ssrc[p] = src[i];
    }
}

// xh = h @ W  (h: [n, D_IN], W: [D_IN, 64]) fused with per-head attention logits.
template <int D_IN>
__global__ __launch_bounds__(256) void k_gemm(const float* __restrict__ h, const float* __restrict__ W,
                                              const float* __restrict__ asrc, const float* __restrict__ adst,
                                              float* __restrict__ xh, float* __restrict__ als,
                                              float* __restrict__ ald, int n) {
    constexpr int HSTR = D_IN + 4;
    __shared__ float hlds[64 * HSTR];
    int t = threadIdx.x;
    int node0 = blockIdx.x * 64;
    constexpr int HTOT = 64 * D_IN / 4;
    for (int i = t; i < HTOT; i += 256) {
        int f = i * 4;
        int nd = f / D_IN, k = f % D_IN;
        float4 val = make_float4(0.f, 0.f, 0.f, 0.f);
        if (node0 + nd < n) val = *(const float4*)(h + (size_t)(node0 + nd) * D_IN + k);
        *(float4*)(hlds + nd * HSTR + k) = val;
    }
    __syncthreads();
    int cg = t & 15, ng = t >> 4;
    float4 acc[4];
#pragma unroll
    for (int i = 0; i < 4; ++i) acc[i] = make_float4(0.f, 0.f, 0.f, 0.f);
    for (int k = 0; k < D_IN; k += 4) {
        float4 w0 = *(const float4*)(W + (size_t)(k + 0) * 64 + cg * 4);
        float4 w1 = *(const float4*)(W + (size_t)(k + 1) * 64 + cg * 4);
        float4 w2 = *(const float4*)(W + (size_t)(k + 2) * 64 + cg * 4);
        float4 w3 = *(const float4*)(W + (size_t)(k + 3) * 64 + cg * 4);
#pragma unroll
        for (int i = 0; i < 4; ++i) {
            float4 hv = *(const float4*)(hlds + (ng * 4 + i) * HSTR + k);
            acc[i].x += hv.x * w0.x + hv.y * w1.x + hv.z * w2.x + hv.w * w3.x;
            acc[i].y += hv.x * w0.y + hv.y * w1.y + hv.z * w2.y + hv.w * w3.y;
            acc[i].z += hv.x * w0.z + hv.y * w1.z + hv.z * w2.z + hv.w * w3.z;
            acc[i].w += hv.x * w0.w + hv.y * w1.w + hv.z * w2.w + hv.w * w3.w;
        }
    }
    float4 as4 = *(const float4*)(asrc + cg * 4);
    float4 ad4 = *(const float4*)(adst + cg * 4);
#pragma unroll
    for (int i = 0; i < 4; ++i) {
        int node = node0 + ng * 4 + i;
        float ps = acc[i].x * as4.x + acc[i].y * as4.y + acc[i].z * as4.z + acc[i].w * as4.w;
        float pd = acc[i].x * ad4.x + acc[i].y * ad4.y + acc[i].z * ad4.z + acc[i].w * ad4.w;
        ps += __shfl_xor(ps, 1, 64);
        ps += __shfl_xor(ps, 2, 64);
        pd += __shfl_xor(pd, 1, 64);
        pd += __shfl_xor(pd, 2, 64);
        if (node < n) {
            *(float4*)(xh + (size_t)node * 64 + cg * 4) = acc[i];
            if ((cg & 3) == 0) {
                als[node * 4 + (cg >> 2)] = ps;
                ald[node * 4 + (cg >> 2)] = pd;
            }
        }
    }
}

__device__ inline float4 lrelu4(float4 v) {
    float4 r;
    r.x = v.x >= 0.f ? v.x : 0.2f * v.x;
    r.y = v.y >= 0.f ? v.y : 0.2f * v.y;
    r.z = v.z >= 0.f ? v.z : 0.2f * v.z;
    r.w = v.w >= 0.f ? v.w : 0.2f * v.w;
    return r;
}

__device__ inline float pick4(float4 v, int h) {
    float r = v.x;
    r = (h == 1) ? v.y : r;
    r = (h == 2) ? v.z : r;
    r = (h == 3) ? v.w : r;
    return r;
}

// One wave per destination node; lane = feature column (head = lane>>4).
// Single pass: m fixed at e_self per head (logit deltas are small; exp stays
// well inside fp32 range, algebraically identical to ref's max-subtraction).
// Per 64-edge chunk: lane-parallel logit computation (each lane does all 4
// heads of one edge), stash (u, pe[4]) in per-wave LDS, then MLP-4 gather loop.
__global__ __launch_bounds__(256) void k_agg(const float* __restrict__ xh, const float* __restrict__ als,
                                             const float* __restrict__ ald, const int* __restrict__ offs,
                                             const int* __restrict__ ssrc, const float* __restrict__ bias,
                                             float* __restrict__ hout, const float* __restrict__ outw,
                                             const float* __restrict__ outb, float* __restrict__ fout, int n) {
    __shared__ int s_u[4][64];
    __shared__ float s_pe[4][64 * 4];
    int wslot = threadIdx.x >> 6;
    int lane = threadIdx.x & 63;
    int v = (blockIdx.x * 256 + threadIdx.x) >> 6;
    if (v >= n) return;
    int head = lane >> 4;
    int* ub = s_u[wslot];
    float* peb = s_pe[wslot];

    int start = offs[v], end = offs[v + 1];
    float4 ald4 = *(const float4*)(ald + 4 * (size_t)v);
    float4 als4v = *(const float4*)(als + 4 * (size_t)v);
    float4 m4 = lrelu4(make_float4(als4v.x + ald4.x, als4v.y + ald4.y, als4v.z + ald4.z, als4v.w + ald4.w));

    float4 zp4 = make_float4(0.f, 0.f, 0.f, 0.f);       // lane-partial z (self handled as +1 later)
    float acc = xh[((size_t)v << 6) + lane];            // self term, pe_self = exp(e_self - m) = 1

    for (int s0 = start; s0 < end; s0 += 64) {
        int cnt = min(64, end - s0);
        bool act = lane < cnt;
        int u = 0;
        float4 alu = make_float4(-1e30f, -1e30f, -1e30f, -1e30f);
        if (act) {
            u = ssrc[s0 + lane];
            alu = *(const float4*)(als + 4 * (size_t)u);
        }
        float4 e4 = lrelu4(make_float4(alu.x + ald4.x, alu.y + ald4.y, alu.z + ald4.z, alu.w + ald4.w));
        float4 pe;
        pe.x = __expf(e4.x - m4.x);   // inactive lanes: exp(-huge) = 0
        pe.y = __expf(e4.y - m4.y);
        pe.z = __expf(e4.z - m4.z);
        pe.w = __expf(e4.w - m4.w);
        zp4.x += pe.x; zp4.y += pe.y; zp4.z += pe.z; zp4.w += pe.w;
        if (act) {
            ub[lane] = u;
            *(float4*)(peb + lane * 4) = pe;
        }
        // LDS written/read by this wave only; compiler inserts lgkmcnt waits.
        int j = 0;
        for (; j + 4 <= cnt; j += 4) {
            int u0 = ub[j + 0], u1 = ub[j + 1], u2 = ub[j + 2], u3 = ub[j + 3];
            float p0 = peb[(j + 0) * 4 + head];
            float p1 = peb[(j + 1) * 4 + head];
            float p2 = peb[(j + 2) * 4 + head];
            float p3 = peb[(j + 3) * 4 + head];
            float x0 = xh[((size_t)u0 << 6) + lane];
            float x1 = xh[((size_t)u1 << 6) + lane];
            float x2 = xh[((size_t)u2 << 6) + lane];
            float x3 = xh[((size_t)u3 << 6) + lane];
            acc += p0 * x0;
            acc += p1 * x1;
            acc += p2 * x2;
            acc += p3 * x3;
        }
        for (; j < cnt; ++j) {
            int u0 = ub[j];
            float p0 = peb[j * 4 + head];
            acc += p0 * xh[((size_t)u0 << 6) + lane];
        }
    }
    // reduce lane-partial z across the wave (once)
#pragma unroll
    for (int d = 1; d < 64; d <<= 1) {
        zp4.x += __shfl_xor(zp4.x, d, 64);
        zp4.y += __shfl_xor(zp4.y, d, 64);
        zp4.z += __shfl_xor(zp4.z, d, 64);
        zp4.w += __shfl_xor(zp4.w, d, 64);
    }
    float z = 1.f + pick4(zp4, head);  // +1 = self edge
    float o = acc / (z + 1e-16f) + bias[lane];
    o = fmaxf(o, 0.f);
    if (outw) {
        float tsum = o * outw[lane];
#pragma unroll
        for (int d = 32; d; d >>= 1) tsum += __shfl_down(tsum, d, 64);
        if (lane == 0) fout[v] = tsum + outb[0];
    } else {
        hout[((size_t)v << 6) + lane] = o;
    }
}

extern "C" void kernel_launch(void* const* d_in, const int* in_sizes, int n_in,
                              void* d_out, int out_size, void* d_ws, size_t ws_size,
                              hipStream_t stream) {
    const float* x = (const float*)d_in[0];
    const int* ei = (const int*)d_in[1];
    const float* w[3] = {(const float*)d_in[2], (const float*)d_in[6], (const float*)d_in[10]};
    const float* as[3] = {(const float*)d_in[3], (const float*)d_in[7], (const float*)d_in[11]};
    const float* ad[3] = {(const float*)d_in[4], (const float*)d_in[8], (const float*)d_in[12]};
    const float* b[3] = {(const float*)d_in[5], (const float*)d_in[9], (const float*)d_in[13]};
    const float* outw = (const float*)d_in[14];
    const float* outb = (const float*)d_in[15];

    const int N = in_sizes[0] / 128;
    const int E = in_sizes[1] / 2;
    const int* src = ei;
    const int* dst = ei + E;

    char* ws = (char*)d_ws;
    auto alloc = [&](size_t bytes) -> void* {
        void* p = (void*)ws;
        ws += (bytes + 255) & ~(size_t)255;
        return p;
    };
    int* counts = (int*)alloc((size_t)N * 4);
    int* offs = (int*)alloc((size_t)(N + 1) * 4);
    int* fill = (int*)alloc((size_t)N * 4);
    int* partials = (int*)alloc(512 * 4);
    int* ssrc = (int*)alloc((size_t)E * 4);
    float* xh = (float*)alloc((size_t)N * 64 * 4);
    float* hbuf = (float*)alloc((size_t)N * 64 * 4);
    float* als = (float*)alloc((size_t)N * 4 * 4);
    float* ald = (float*)alloc((size_t)N * 4 * 4);

    const int nblk = (N + 255) / 256;
    k_zero<<<(N + 255) / 256, 256, 0, stream>>>(counts, N);
    k_hist<<<(E + 255) / 256, 256, 0, stream>>>(dst, counts, E);
    k_scan_a<<<nblk, 256, 0, stream>>>(counts, partials, N);
    k_scan_b<<<1, 512, 0, stream>>>(partials, nblk);
    k_scan_c<<<nblk, 256, 0, stream>>>(counts, partials, offs, fill, N);
    k_scatter<<<(E + 255) / 256, 256, 0, stream>>>(src, dst, fill, ssrc, E);

    const int gblocks = (N + 63) / 64;
    const int ablocks = (N + 3) / 4;

    k_gemm<128><<<gblocks, 256, 0, stream>>>(x, w[0], as[0], ad[0], xh, als, ald, N);
    k_agg<<<ablocks, 256, 0, stream>>>(xh, als, ald, offs, ssrc, b[0], hbuf, nullptr, nullptr, nullptr, N);
    k_gemm<64><<<gblocks, 256, 0, stream>>>(hbuf, w[1], as[1], ad[1], xh, als, ald, N);
    k_agg<<<ablocks, 256, 0, stream>>>(xh, als, ald, offs, ssrc, b[1], hbuf, nullptr, nullptr, nullptr, N);
    k_gemm<64><<<gblocks, 256, 0, stream>>>(hbuf, w[2], as[2], ad[2], xh, als, ald, N);
    k_agg<<<ablocks, 256, 0, stream>>>(xh, als, ald, offs, ssrc, b[2], nullptr, outw, outb, (float*)d_out, N);
}

// Round 3
// 550.022 us; speedup vs baseline: 2.1344x; 1.2796x over previous
//
#include <hip/hip_runtime.h>

// GAT node regressor: 3 GAT layers (HID=64, 4 heads x 16) + linear head.
// CSR-by-dst built once per call via bucketed counting sort (no random global
// scatter): k_bhist (LDS hist of dst>>8) -> k_bscan -> k_bscatter (block-local
// LDS counting sort, streamed run-writes) -> k_bfinal (per-bucket 256-bin sort,
// fully coalesced offs/ssrc writes). Then per layer:
//   k_gemm: xh = h@W (LDS-tiled fp32) fused with al_s/al_d head reductions
//   k_agg : wave-per-dst-node gather, single pass (m fixed at e_self per head),
//           chunked lane-parallel logits in LDS + MLP-4 xh-row gather loop.
//           Layer 2 fuses the final h@out_w dot via wave shfl reduction.

#define NBMAX 512   // max dst buckets (dst>>8); N=100K -> 391
#define SCHUNK 4096 // edges per k_bscatter block
#define BCAP 8192   // per-bucket LDS src capacity in k_bfinal (avg 4096)

__global__ __launch_bounds__(256) void k_zero(int* p, int n) {
    int i = blockIdx.x * 256 + threadIdx.x;
    if (i < n) p[i] = 0;
}

__global__ __launch_bounds__(256) void k_bhist(const int* __restrict__ dst, int* __restrict__ bhist, int e) {
    __shared__ unsigned int h[NBMAX];
    int t = threadIdx.x;
    h[t] = 0;
    h[t + 256] = 0;
    __syncthreads();
    for (int i = blockIdx.x * 256 + t; i < e; i += gridDim.x * 256)
        atomicAdd(&h[dst[i] >> 8], 1u);
    __syncthreads();
    if (h[t]) atomicAdd(&bhist[t], (int)h[t]);
    if (h[t + 256]) atomicAdd(&bhist[t + 256], (int)h[t + 256]);
}

__global__ __launch_bounds__(512) void k_bscan(const int* __restrict__ bhist, int* __restrict__ boffs,
                                               int* __restrict__ bfill, int nb, int e) {
    __shared__ int s[NBMAX];
    int t = threadIdx.x;
    int v = (t < nb) ? bhist[t] : 0;
    s[t] = v;
    __syncthreads();
    for (int o = 1; o < 512; o <<= 1) {
        int add = (t >= o) ? s[t - o] : 0;
        __syncthreads();
        s[t] += add;
        __syncthreads();
    }
    boffs[t] = s[t] - v;  // exclusive
    if (t == 511) boffs[512] = s[511];
    bfill[t] = 0;
}

// Block-local counting sort of a 4096-edge chunk by dst>>8, then streamed
// writes of sorted runs (consecutive threads -> consecutive addresses within
// each ~10-edge bucket run). Packs src (17b) | (dst&255)<<24 into 4B.
__global__ __launch_bounds__(512) void k_bscatter(const int* __restrict__ src, const int* __restrict__ dst,
                                                  const int* __restrict__ boffs, int* __restrict__ bfill,
                                                  unsigned int* __restrict__ edata, int e) {
    __shared__ unsigned int hist[NBMAX];   // counts, then cursor
    __shared__ unsigned int loc[NBMAX];    // local exclusive offsets
    __shared__ int gbase[NBMAX];
    __shared__ unsigned int stmp[NBMAX];
    __shared__ unsigned int sortbuf[SCHUNK];
    __shared__ int posbuf[SCHUNK];
    int t = threadIdx.x;
    int i0 = blockIdx.x * SCHUNK;
    int cnt = min(SCHUNK, e - i0);
    hist[t] = 0;
    __syncthreads();
    for (int j = t; j < cnt; j += 512) atomicAdd(&hist[dst[i0 + j] >> 8], 1u);
    __syncthreads();
    unsigned int v = hist[t];
    stmp[t] = v;
    __syncthreads();
    for (int o = 1; o < 512; o <<= 1) {
        unsigned int add = (t >= o) ? stmp[t - o] : 0;
        __syncthreads();
        stmp[t] += add;
        __syncthreads();
    }
    loc[t] = stmp[t] - v;
    int gb = 0;
    if (v > 0) gb = atomicAdd(&bfill[t], (int)v);  // reserve contiguous run in bucket t
    gbase[t] = boffs[t] + gb - (int)loc[t];
    hist[t] = loc[t];  // cursor
    __syncthreads();
    for (int j = t; j < cnt; j += 512) {
        int d = dst[i0 + j];
        int s = src[i0 + j];
        int b = d >> 8;
        unsigned int p = atomicAdd(&hist[b], 1u);
        sortbuf[p] = (unsigned int)s | ((unsigned int)(d & 255) << 24);
        posbuf[p] = gbase[b] + (int)p;
    }
    __syncthreads();
    for (int j = t; j < cnt; j += 512) edata[posbuf[j]] = sortbuf[j];
}

// One block per bucket: 256-bin counting sort of the bucket's edges by local
// dst; writes offs (coalesced) and ssrc (coalesced via LDS staging).
__global__ __launch_bounds__(256) void k_bfinal(const unsigned int* __restrict__ edata,
                                                const int* __restrict__ boffs, int* __restrict__ offs,
                                                int* __restrict__ ssrc, int n, int nb) {
    __shared__ unsigned int hist[256];
    __shared__ unsigned int stmp[256];
    __shared__ unsigned int loc[256];
    __shared__ unsigned int srcbuf[BCAP];
    int b = blockIdx.x;
    int t = threadIdx.x;
    int e0 = boffs[b], e1 = boffs[b + 1];
    int cnt = e1 - e0;
    hist[t] = 0;
    __syncthreads();
    for (int j = t; j < cnt; j += 256) atomicAdd(&hist[edata[e0 + j] >> 24], 1u);
    __syncthreads();
    unsigned int v = hist[t];
    stmp[t] = v;
    __syncthreads();
    for (int o = 1; o < 256; o <<= 1) {
        unsigned int add = (t >= o) ? stmp[t - o] : 0;
        __syncthreads();
        stmp[t] += add;
        __syncthreads();
    }
    loc[t] = stmp[t] - v;
    int node = b * 256 + t;
    if (node < n) offs[node] = e0 + (int)loc[t];
    if (b == nb - 1 && t == 0) offs[n] = e1;
    hist[t] = loc[t];  // cursor
    __syncthreads();
    if (cnt <= BCAP) {
        for (int j = t; j < cnt; j += 256) {
            unsigned int p = edata[e0 + j];
            unsigned int pos = atomicAdd(&hist[p >> 24], 1u);
            srcbuf[pos] = p & 0xFFFFFFu;
        }
        __syncthreads();
        for (int j = t; j < cnt; j += 256) ssrc[e0 + j] = (int)srcbuf[j];
    } else {  // safety fallback (never hit for Poisson(4096) buckets)
        for (int j = t; j < cnt; j += 256) {
            unsigned int p = edata[e0 + j];
            unsigned int pos = atomicAdd(&hist[p >> 24], 1u);
            ssrc[e0 + (int)pos] = (int)(p & 0xFFFFFFu);
        }
    }
}

// xh = h @ W  (h: [n, D_IN], W: [D_IN, 64]) fused with per-head attention logits.
template <int D_IN>
__global__ __launch_bounds__(256) void k_gemm(const float* __restrict__ h, const float* __restrict__ W,
                                              const float* __restrict__ asrc, const float* __restrict__ adst,
                                              float* __restrict__ xh, float* __restrict__ als,
                                              float* __restrict__ ald, int n) {
    constexpr int HSTR = D_IN + 4;
    __shared__ float hlds[64 * HSTR];
    int t = threadIdx.x;
    int node0 = blockIdx.x * 64;
    constexpr int HTOT = 64 * D_IN / 4;
    for (int i = t; i < HTOT; i += 256) {
        int f = i * 4;
        int nd = f / D_IN, k = f % D_IN;
        float4 val = make_float4(0.f, 0.f, 0.f, 0.f);
        if (node0 + nd < n) val = *(const float4*)(h + (size_t)(node0 + nd) * D_IN + k);
        *(float4*)(hlds + nd * HSTR + k) = val;
    }
    __syncthreads();
    int cg = t & 15, ng = t >> 4;
    float4 acc[4];
#pragma unroll
    for (int i = 0; i < 4; ++i) acc[i] = make_float4(0.f, 0.f, 0.f, 0.f);
    for (int k = 0; k < D_IN; k += 4) {
        float4 w0 = *(const float4*)(W + (size_t)(k + 0) * 64 + cg * 4);
        float4 w1 = *(const float4*)(W + (size_t)(k + 1) * 64 + cg * 4);
        float4 w2 = *(const float4*)(W + (size_t)(k + 2) * 64 + cg * 4);
        float4 w3 = *(const float4*)(W + (size_t)(k + 3) * 64 + cg * 4);
#pragma unroll
        for (int i = 0; i < 4; ++i) {
            float4 hv = *(const float4*)(hlds + (ng * 4 + i) * HSTR + k);
            acc[i].x += hv.x * w0.x + hv.y * w1.x + hv.z * w2.x + hv.w * w3.x;
            acc[i].y += hv.x * w0.y + hv.y * w1.y + hv.z * w2.y + hv.w * w3.y;
            acc[i].z += hv.x * w0.z + hv.y * w1.z + hv.z * w2.z + hv.w * w3.z;
            acc[i].w += hv.x * w0.w + hv.y * w1.w + hv.z * w2.w + hv.w * w3.w;
        }
    }
    float4 as4 = *(const float4*)(asrc + cg * 4);
    float4 ad4 = *(const float4*)(adst + cg * 4);
#pragma unroll
    for (int i = 0; i < 4; ++i) {
        int node = node0 + ng * 4 + i;
        float ps = acc[i].x * as4.x + acc[i].y * as4.y + acc[i].z * as4.z + acc[i].w * as4.w;
        float pd = acc[i].x * ad4.x + acc[i].y * ad4.y + acc[i].z * ad4.z + acc[i].w * ad4.w;
        ps += __shfl_xor(ps, 1, 64);
        ps += __shfl_xor(ps, 2, 64);
        pd += __shfl_xor(pd, 1, 64);
        pd += __shfl_xor(pd, 2, 64);
        if (node < n) {
            *(float4*)(xh + (size_t)node * 64 + cg * 4) = acc[i];
            if ((cg & 3) == 0) {
                als[node * 4 + (cg >> 2)] = ps;
                ald[node * 4 + (cg >> 2)] = pd;
            }
        }
    }
}

__device__ inline float4 lrelu4(float4 v) {
    float4 r;
    r.x = v.x >= 0.f ? v.x : 0.2f * v.x;
    r.y = v.y >= 0.f ? v.y : 0.2f * v.y;
    r.z = v.z >= 0.f ? v.z : 0.2f * v.z;
    r.w = v.w >= 0.f ? v.w : 0.2f * v.w;
    return r;
}

__device__ inline float pick4(float4 v, int h) {
    float r = v.x;
    r = (h == 1) ? v.y : r;
    r = (h == 2) ? v.z : r;
    r = (h == 3) ? v.w : r;
    return r;
}

// One wave per destination node; lane = feature column (head = lane>>4).
// Single pass: m fixed at e_self per head (algebraically identical to ref's
// max-subtraction; exp deltas stay well inside fp32 range).
__global__ __launch_bounds__(256) void k_agg(const float* __restrict__ xh, const float* __restrict__ als,
                                             const float* __restrict__ ald, const int* __restrict__ offs,
                                             const int* __restrict__ ssrc, const float* __restrict__ bias,
                                             float* __restrict__ hout, const float* __restrict__ outw,
                                             const float* __restrict__ outb, float* __restrict__ fout, int n) {
    __shared__ int s_u[4][64];
    __shared__ float s_pe[4][64 * 4];
    int wslot = threadIdx.x >> 6;
    int lane = threadIdx.x & 63;
    int v = (blockIdx.x * 256 + threadIdx.x) >> 6;
    if (v >= n) return;
    int head = lane >> 4;
    int* ub = s_u[wslot];
    float* peb = s_pe[wslot];

    int start = offs[v], end = offs[v + 1];
    float4 ald4 = *(const float4*)(ald + 4 * (size_t)v);
    float4 als4v = *(const float4*)(als + 4 * (size_t)v);
    float4 m4 = lrelu4(make_float4(als4v.x + ald4.x, als4v.y + ald4.y, als4v.z + ald4.z, als4v.w + ald4.w));

    float4 zp4 = make_float4(0.f, 0.f, 0.f, 0.f);
    float acc = xh[((size_t)v << 6) + lane];  // self term, pe_self = 1

    for (int s0 = start; s0 < end; s0 += 64) {
        int cnt = min(64, end - s0);
        bool act = lane < cnt;
        int u = 0;
        float4 alu = make_float4(-1e30f, -1e30f, -1e30f, -1e30f);
        if (act) {
            u = ssrc[s0 + lane];
            alu = *(const float4*)(als + 4 * (size_t)u);
        }
        float4 e4 = lrelu4(make_float4(alu.x + ald4.x, alu.y + ald4.y, alu.z + ald4.z, alu.w + ald4.w));
        float4 pe;
        pe.x = __expf(e4.x - m4.x);
        pe.y = __expf(e4.y - m4.y);
        pe.z = __expf(e4.z - m4.z);
        pe.w = __expf(e4.w - m4.w);
        zp4.x += pe.x; zp4.y += pe.y; zp4.z += pe.z; zp4.w += pe.w;
        if (act) {
            ub[lane] = u;
            *(float4*)(peb + lane * 4) = pe;
        }
        int j = 0;
        for (; j + 4 <= cnt; j += 4) {
            int u0 = ub[j + 0], u1 = ub[j + 1], u2 = ub[j + 2], u3 = ub[j + 3];
            float p0 = peb[(j + 0) * 4 + head];
            float p1 = peb[(j + 1) * 4 + head];
            float p2 = peb[(j + 2) * 4 + head];
            float p3 = peb[(j + 3) * 4 + head];
            float x0 = xh[((size_t)u0 << 6) + lane];
            float x1 = xh[((size_t)u1 << 6) + lane];
            float x2 = xh[((size_t)u2 << 6) + lane];
            float x3 = xh[((size_t)u3 << 6) + lane];
            acc += p0 * x0;
            acc += p1 * x1;
            acc += p2 * x2;
            acc += p3 * x3;
        }
        for (; j < cnt; ++j) {
            int u0 = ub[j];
            float p0 = peb[j * 4 + head];
            acc += p0 * xh[((size_t)u0 << 6) + lane];
        }
    }
#pragma unroll
    for (int d = 1; d < 64; d <<= 1) {
        zp4.x += __shfl_xor(zp4.x, d, 64);
        zp4.y += __shfl_xor(zp4.y, d, 64);
        zp4.z += __shfl_xor(zp4.z, d, 64);
        zp4.w += __shfl_xor(zp4.w, d, 64);
    }
    float z = 1.f + pick4(zp4, head);  // +1 = self edge
    float o = acc / (z + 1e-16f) + bias[lane];
    o = fmaxf(o, 0.f);
    if (outw) {
        float tsum = o * outw[lane];
#pragma unroll
        for (int d = 32; d; d >>= 1) tsum += __shfl_down(tsum, d, 64);
        if (lane == 0) fout[v] = tsum + outb[0];
    } else {
        hout[((size_t)v << 6) + lane] = o;
    }
}

extern "C" void kernel_launch(void* const* d_in, const int* in_sizes, int n_in,
                              void* d_out, int out_size, void* d_ws, size_t ws_size,
                              hipStream_t stream) {
    const float* x = (const float*)d_in[0];
    const int* ei = (const int*)d_in[1];
    const float* w[3] = {(const float*)d_in[2], (const float*)d_in[6], (const float*)d_in[10]};
    const float* as[3] = {(const float*)d_in[3], (const float*)d_in[7], (const float*)d_in[11]};
    const float* ad[3] = {(const float*)d_in[4], (const float*)d_in[8], (const float*)d_in[12]};
    const float* b[3] = {(const float*)d_in[5], (const float*)d_in[9], (const float*)d_in[13]};
    const float* outw = (const float*)d_in[14];
    const float* outb = (const float*)d_in[15];

    const int N = in_sizes[0] / 128;
    const int E = in_sizes[1] / 2;
    const int* src = ei;
    const int* dst = ei + E;
    const int NB = (N + 255) / 256;  // 391 <= NBMAX

    char* ws = (char*)d_ws;
    auto alloc = [&](size_t bytes) -> void* {
        void* p = (void*)ws;
        ws += (bytes + 255) & ~(size_t)255;
        return p;
    };
    int* bhist = (int*)alloc(NBMAX * 4);
    int* boffs = (int*)alloc((NBMAX + 1) * 4);
    int* bfill = (int*)alloc(NBMAX * 4);
    int* offs = (int*)alloc((size_t)(N + 1) * 4);
    int* ssrc = (int*)alloc((size_t)E * 4);
    float* xh = (float*)alloc((size_t)N * 64 * 4);
    float* hbuf = (float*)alloc((size_t)N * 64 * 4);
    float* als = (float*)alloc((size_t)N * 4 * 4);
    float* ald = (float*)alloc((size_t)N * 4 * 4);
    // edata (E*4B) aliases xh (N*256B): dead before the first k_gemm writes xh
    // (same-stream kernels serialize).
    unsigned int* edata = (unsigned int*)xh;

    k_zero<<<(NBMAX + 255) / 256, 256, 0, stream>>>(bhist, NBMAX);
    k_bhist<<<256, 256, 0, stream>>>(dst, bhist, E);
    k_bscan<<<1, 512, 0, stream>>>(bhist, boffs, bfill, NB, E);
    k_bscatter<<<(E + SCHUNK - 1) / SCHUNK, 512, 0, stream>>>(src, dst, boffs, bfill, edata, E);
    k_bfinal<<<NB, 256, 0, stream>>>(edata, boffs, offs, ssrc, N, NB);

    const int gblocks = (N + 63) / 64;
    const int ablocks = (N + 3) / 4;

    k_gemm<128><<<gblocks, 256, 0, stream>>>(x, w[0], as[0], ad[0], xh, als, ald, N);
    k_agg<<<ablocks, 256, 0, stream>>>(xh, als, ald, offs, ssrc, b[0], hbuf, nullptr, nullptr, nullptr, N);
    k_gemm<64><<<gblocks, 256, 0, stream>>>(hbuf, w[1], as[1], ad[1], xh, als, ald, N);
    k_agg<<<ablocks, 256, 0, stream>>>(xh, als, ald, offs, ssrc, b[1], hbuf, nullptr, nullptr, nullptr, N);
    k_gemm<64><<<gblocks, 256, 0, stream>>>(hbuf, w[2], as[2], ad[2], xh, als, ald, N);
    k_agg<<<ablocks, 256, 0, stream>>>(xh, als, ald, offs, ssrc, b[2], nullptr, outw, outb, (float*)d_out, N);
}